// Round 10
// baseline (13435.074 us; speedup 1.0000x reference)
//
#include <hip/hip_runtime.h>

constexpr int kB = 64;
constexpr int kT = 1024;
constexpr int kC = 128;
constexpr int kH = 512;

constexpr int kWgPerGrp = 32;   // wgs per group (16 cols each)
constexpr int kRows     = 4;    // batches per group
constexpr int kHStrF    = 520;  // hbuf row: 512 h + 8 pad floats
constexpr int kXStrF    = 132;  // xbuf row: 128 x + 4 pad floats

#define SCOPE_AGENT __HIP_MEMORY_SCOPE_AGENT

__device__ __forceinline__ float sigmoidf_(float v) {
    return 1.0f / (1.0f + __expf(-v));
}

// Persistent GRU. 512 wgs x 256 threads (4 waves), 2 wgs/CU (12.5KB LDS).
// 16 groups x 32 wgs, R7 mapping (each XCD hosts 2 groups; each CU one wg of
// each -> anti-phased latency hiding). Group g owns batches [g*4, g*4+4);
// wg owns output columns [jb*16, jb*16+16).
// h-exchange through hs_out (R5/R7-proven): finishers publish with relaxed
// agent-scope atomic stores (MALL-visible, bypass L1/L2); consumers stage
// hs_out[:, t-1, :] with plain coalesced float4 loads — fresh addresses each
// step, no cache can hold a stale copy.
// R10 chain trims vs R7:
//  - x-part FMAs moved BEFORE the poll (h-independent; x double-buffered in
//    LDS, next-step x load issued pre-poll so HBM latency hides under spin).
//  - per-WAVE flags (128/group): wave publishes -> s_waitcnt vmcnt(0) (asm,
//    wave-local) -> flag store; ALL lanes poll 2 flags each -> each wave
//    self-releases. Replaces [sync+flag+poll(tid<32)+sync]: 2 syncthreads
//    deleted; ONE syncthreads/step remains (stage->compute visibility).
//  - cross-wave hbuf WAR safety WITHOUT end-of-loop sync: wave A stages(t+1)
//    only after poll(t+1) passes, which needs wave B's flag(t+1), set after
//    B's step-t hbuf reads. x double-buffer: slot (t+1)&1 written pre-SYNC(t),
//    read at t+1 (after SYNC(t)); old readers of that slot finished before
//    SYNC(t-1). All orderings hold without placement assumptions.
// Weights in registers (R7): whR[4][3][2] + wiR[3][2]. Thread map tid =
// jp(3b)|s(5b), strided K-split k4 = s+32m; reduce-scatter xor{8,4,2} +
// butterflies xor{16,1}; finishers = even lanes s<16.
__global__ __launch_bounds__(256, 2)
void gru_seq_kernel(const float* __restrict__ x,
                    const float* __restrict__ h0,
                    const float* __restrict__ w_ih,
                    const float* __restrict__ w_hh,
                    const float* __restrict__ b_ih,
                    const float* __restrict__ b_hh,
                    float* __restrict__ hs_out,    // d_out, [B,T,H]
                    float* __restrict__ h_final,   // d_out + B*T*H
                    unsigned* __restrict__ flags)  // d_ws: 16 x 128 wave-flags
{
    const int wg   = blockIdx.x;
    const int q    = wg >> 3;
    const int grp  = ((wg & 7) << 1) | (q & 1);  // 0..15
    const int jb   = q >> 1;                     // 0..31
    const int tid  = threadIdx.x;
    const int jp   = tid >> 5;                   // 0..7 (j-pair)
    const int s    = tid & 31;                   // K-slice
    const int lane = tid & 63;
    const int wv   = tid >> 6;                   // wave id 0..3
    const int b0   = grp * kRows;

    __shared__ float hbuf[kRows][kHStrF];        // 8,320 B
    __shared__ float xbuf[2][kRows][kXStrF];     // 4,224 B

    // ---- one-time weight loads into REGISTERS (R7-verbatim) ----
    const float4* w_hh4 = (const float4*)w_hh;
    const float4* w_ih4 = (const float4*)w_ih;
    float4 whR[4][3][2];
    #pragma unroll
    for (int m = 0; m < 4; ++m)
        #pragma unroll
        for (int g = 0; g < 3; ++g)
            #pragma unroll
            for (int jj = 0; jj < 2; ++jj)
                whR[m][g][jj] =
                    w_hh4[((size_t)(g * kH + jb * 16 + jp * 2 + jj)) * (kH / 4)
                          + s + 32 * m];
    float4 wiR[3][2];
    #pragma unroll
    for (int g = 0; g < 3; ++g)
        #pragma unroll
        for (int jj = 0; jj < 2; ++jj)
            wiR[g][jj] =
                w_ih4[((size_t)(g * kH + jb * 16 + jp * 2 + jj)) * (kC / 4) + s];

    const int jg_f = jb * 16 + jp * 2 + ((s >> 1) & 1);
    const float brz = b_ih[jg_f]          + b_hh[jg_f];
    const float bzz = b_ih[kH + jg_f]     + b_hh[kH + jg_f];
    const float bxn = b_ih[2 * kH + jg_f];
    const float bhn = b_hh[2 * kH + jg_f];

    unsigned* gflags = flags + grp * 128;
    unsigned* myflag = gflags + jb * 4 + wv;

    // ---- prologue: stage h0 and x(0) ----
    #pragma unroll
    for (int qq = 0; qq < 2; ++qq) {
        const int idx = tid + qq * 256;
        const int row = idx >> 7;
        const int f4  = idx & 127;
        *(float4*)&hbuf[row][f4 * 4] =
            *(const float4*)&h0[(size_t)(b0 + row) * kH + f4 * 4];
    }
    if (tid < 128) {
        const int row = tid >> 5;
        const int f4i = tid & 31;
        *(float4*)&xbuf[0][row][f4i * 4] =
            *(const float4*)&x[((size_t)(b0 + row) * kT + 0) * kC + f4i * 4];
    }
    __syncthreads();

    for (int t = 0; t < kT; ++t) {
        float acc[4][4][2];
        #pragma unroll
        for (int g = 0; g < 4; ++g)
            #pragma unroll
            for (int i = 0; i < 4; ++i) {
                acc[g][i][0] = 0.f; acc[g][i][1] = 0.f;
            }

        // ---- x-part FMAs (h-independent, runs before/through the wait) ----
        {
            float4 x4v[4];
            #pragma unroll
            for (int i = 0; i < 4; ++i)
                x4v[i] = *(const float4*)(&xbuf[t & 1][i][s * 4]);
            #pragma unroll
            for (int g = 0; g < 3; ++g) {
                const int ga = (g == 2) ? 3 : g;   // x-side n -> acc[3]
                #pragma unroll
                for (int jj = 0; jj < 2; ++jj) {
                    const float4 w4 = wiR[g][jj];
                    #pragma unroll
                    for (int i = 0; i < 4; ++i)
                        acc[ga][i][jj] += x4v[i].x * w4.x + x4v[i].y * w4.y
                                        + x4v[i].z * w4.z + x4v[i].w * w4.w;
                }
            }
        }

        // ---- issue x(t+1) load (latency hides under the poll) ----
        float4 xnext = make_float4(0.f, 0.f, 0.f, 0.f);
        if (t + 1 < kT && tid < 128) {
            const int row = tid >> 5;
            const int f4i = tid & 31;
            xnext = *(const float4*)
                &x[((size_t)(b0 + row) * kT + (t + 1)) * kC + f4i * 4];
        }

        // ---- all-lane poll: each wave self-releases ----
        if (t > 0) {
            const unsigned e = (unsigned)t;
            unsigned v1, v2;
            do {
                v1 = __hip_atomic_load(gflags + lane,      __ATOMIC_RELAXED, SCOPE_AGENT);
                v2 = __hip_atomic_load(gflags + 64 + lane, __ATOMIC_RELAXED, SCOPE_AGENT);
            } while (__any((int)((v1 < e) || (v2 < e))));
        }

        // ---- x(t+1) LDS write (slot (t+1)&1; pre-SYNC per WAR proof) ----
        if (t + 1 < kT && tid < 128) {
            const int row = tid >> 5;
            const int f4i = tid & 31;
            *(float4*)&xbuf[(t + 1) & 1][row][f4i * 4] = xnext;
        }

        // ---- stage h(t-1): plain coalesced float4 (fresh addresses) ----
        if (t > 0) {
            #pragma unroll
            for (int qq = 0; qq < 2; ++qq) {
                const int idx = tid + qq * 256;
                const int row = idx >> 7;
                const int f4  = idx & 127;
                *(float4*)&hbuf[row][f4 * 4] = *(const float4*)
                    &hs_out[((size_t)(b0 + row) * kT + (t - 1)) * kH + f4 * 4];
            }
        }
        __syncthreads();   // the ONE per-step sync: staging visible to all waves

        // ---- h-part FMAs (R7-verbatim) ----
        const float* hbase = &hbuf[0][s * 4];
        #pragma unroll
        for (int m = 0; m < 4; ++m) {
            const int off = m * 128;
            float4 h4[4];
            #pragma unroll
            for (int i = 0; i < 4; ++i)
                h4[i] = *(const float4*)(hbase + i * kHStrF + off);
            #pragma unroll
            for (int g = 0; g < 3; ++g)
                #pragma unroll
                for (int jj = 0; jj < 2; ++jj) {
                    const float4 w4 = whR[m][g][jj];
                    #pragma unroll
                    for (int i = 0; i < 4; ++i)
                        acc[g][i][jj] += h4[i].x * w4.x + h4[i].y * w4.y
                                       + h4[i].z * w4.z + h4[i].w * w4.w;
                }
        }

        // ---- reduce-scatter xor{8,4,2} + butterflies xor{16,1} (R7) ----
        const bool b3 = (s >> 3) & 1;
        const bool b2 = (s >> 2) & 1;
        const bool b1 = (s >> 1) & 1;

        float A[4][2][2];
        #pragma unroll
        for (int g = 0; g < 4; ++g)
            #pragma unroll
            for (int ii = 0; ii < 2; ++ii)
                #pragma unroll
                for (int jj = 0; jj < 2; ++jj) {
                    const float keep = b3 ? acc[g][2 + ii][jj] : acc[g][ii][jj];
                    const float send = b3 ? acc[g][ii][jj] : acc[g][2 + ii][jj];
                    A[g][ii][jj] = keep + __shfl_xor(send, 8);
                }
        float Bv[4][2];
        #pragma unroll
        for (int g = 0; g < 4; ++g)
            #pragma unroll
            for (int jj = 0; jj < 2; ++jj) {
                const float keep = b2 ? A[g][1][jj] : A[g][0][jj];
                const float send = b2 ? A[g][0][jj] : A[g][1][jj];
                Bv[g][jj] = keep + __shfl_xor(send, 4);
            }
        float Dv[4];
        #pragma unroll
        for (int g = 0; g < 4; ++g) {
            const float keep = b1 ? Bv[g][1] : Bv[g][0];
            const float send = b1 ? Bv[g][0] : Bv[g][1];
            float c = keep + __shfl_xor(send, 2);
            c += __shfl_xor(c, 16);
            c += __shfl_xor(c, 1);
            Dv[g] = c;
        }

        // ---- finish + publish (even lanes s<16; row = b3*2+b2, jj = b1) ----
        if (s < 16 && (s & 1) == 0) {
            const int   row  = ((s >> 3) & 1) * 2 + ((s >> 2) & 1);
            const int   bg   = b0 + row;
            const float rg   = sigmoidf_(Dv[0] + brz);
            const float zg   = sigmoidf_(Dv[1] + bzz);
            const float ng   = tanhf(Dv[3] + bxn + rg * (Dv[2] + bhn));
            const float hold = hbuf[row][jg_f];
            const float hnew = (1.f - zg) * ng + zg * hold;

            __hip_atomic_store(&hs_out[((size_t)bg * kT + t) * kH + jg_f], hnew,
                               __ATOMIC_RELAXED, SCOPE_AGENT);
            if (t == kT - 1) h_final[(size_t)bg * kH + jg_f] = hnew;
        }

        // ---- wave-local drain, then per-wave flag (no syncthreads) ----
        asm volatile("s_waitcnt vmcnt(0) lgkmcnt(0)" ::: "memory");
        if (lane == 0)
            __hip_atomic_store(myflag, (unsigned)(t + 1),
                               __ATOMIC_RELAXED, SCOPE_AGENT);
    }
}

// 32x32 tiled transpose: wpT[k][d] = w_post[d][k].
__global__ __launch_bounds__(256)
void wpt_kernel(const float* __restrict__ w_post, float* __restrict__ wpT)
{
    __shared__ float tile[32][33];
    const int bx = blockIdx.x & 15, by = blockIdx.x >> 4;
    const int tx = threadIdx.x & 31, ty = threadIdx.x >> 5;   // 32 x 8
    #pragma unroll
    for (int i = 0; i < 4; ++i)
        tile[ty + i * 8][tx] =
            w_post[(size_t)(by * 32 + ty + i * 8) * kH + bx * 32 + tx];
    __syncthreads();
    #pragma unroll
    for (int i = 0; i < 4; ++i)
        wpT[(size_t)(bx * 32 + ty + i * 8) * kH + by * 32 + tx] =
            tile[tx][ty + i * 8];
}

// In-place post projection, coalesced-w version:
// out[b,t,:] = relu(hs[b,t,:] @ w_post^T + b_post), using wpT[k][d].
// 4096 blocks x 128 thr; block owns 16 rows; thread owns d = tid*4..+3.
// w-loads: wpT4[k*128 + tid] -> 64 lanes consecutive 16B = coalesced.
__global__ __launch_bounds__(128)
void post2_kernel(const float* __restrict__ wpT,
                  const float* __restrict__ b_post,
                  float* __restrict__ out)
{
    __shared__ float hb[16][kH];
    const int tid = threadIdx.x;
    const size_t row0 = (size_t)blockIdx.x * 16;

    const float4* src = (const float4*)(out + row0 * kH);
    float4* hb4 = (float4*)hb;
    for (int i = tid; i < 16 * kH / 4; i += 128) hb4[i] = src[i];
    __syncthreads();

    float4 acc[16];
    #pragma unroll
    for (int m = 0; m < 16; ++m) acc[m] = make_float4(0.f, 0.f, 0.f, 0.f);

    const float4* wT4 = (const float4*)wpT;
    for (int k4 = 0; k4 < kH / 4; ++k4) {
        const float4 w0 = wT4[(size_t)(k4 * 4 + 0) * 128 + tid];
        const float4 w1 = wT4[(size_t)(k4 * 4 + 1) * 128 + tid];
        const float4 w2 = wT4[(size_t)(k4 * 4 + 2) * 128 + tid];
        const float4 w3 = wT4[(size_t)(k4 * 4 + 3) * 128 + tid];
        #pragma unroll
        for (int m = 0; m < 16; ++m) {
            const float4 h4 = *(const float4*)&hb[m][k4 * 4];
            acc[m].x += h4.x * w0.x + h4.y * w1.x + h4.z * w2.x + h4.w * w3.x;
            acc[m].y += h4.x * w0.y + h4.y * w1.y + h4.z * w2.y + h4.w * w3.y;
            acc[m].z += h4.x * w0.z + h4.y * w1.z + h4.z * w2.z + h4.w * w3.z;
            acc[m].w += h4.x * w0.w + h4.y * w1.w + h4.z * w2.w + h4.w * w3.w;
        }
    }

    const float4 bp = *(const float4*)&b_post[tid * 4];
    #pragma unroll
    for (int m = 0; m < 16; ++m) {
        float4 r;
        r.x = fmaxf(acc[m].x + bp.x, 0.f);
        r.y = fmaxf(acc[m].y + bp.y, 0.f);
        r.z = fmaxf(acc[m].z + bp.z, 0.f);
        r.w = fmaxf(acc[m].w + bp.w, 0.f);
        *(float4*)&out[(row0 + m) * kH + tid * 4] = r;
    }
}

extern "C" void kernel_launch(void* const* d_in, const int* in_sizes, int n_in,
                              void* d_out, int out_size, void* d_ws, size_t ws_size,
                              hipStream_t stream) {
    const float* x      = (const float*)d_in[0];
    const float* h0     = (const float*)d_in[1];
    const float* w_ih   = (const float*)d_in[2];
    const float* w_hh   = (const float*)d_in[3];
    const float* b_ih   = (const float*)d_in[4];
    const float* b_hh   = (const float*)d_in[5];
    const float* w_post = (const float*)d_in[6];
    const float* b_post = (const float*)d_in[7];

    float* out     = (float*)d_out;
    float* h_final = out + (size_t)kB * kT * kH;

    unsigned* flags = (unsigned*)d_ws;                  // 16 x 128 u32 = 8 KB
    float* wpT      = (float*)((char*)d_ws + 8192);     // 512 x 512 = 1 MB

    // flags must start at 0 every launch (d_ws is not re-poisoned per replay)
    hipMemsetAsync(d_ws, 0, 8192, stream);

    // transpose w_post (independent; stream-ordered before post2)
    wpt_kernel<<<dim3(256), dim3(256), 0, stream>>>(w_post, wpT);

    void* args[] = { (void*)&x, (void*)&h0, (void*)&w_ih, (void*)&w_hh,
                     (void*)&b_ih, (void*)&b_hh, (void*)&out, (void*)&h_final,
                     (void*)&flags };
    // Cooperative launch for guaranteed co-residency; fall back to plain
    // launch if refused (512 wgs at 2/CU co-resident in practice).
    hipError_t err = hipLaunchCooperativeKernel((void*)gru_seq_kernel,
                                                dim3(512), dim3(256),
                                                args, 0, stream);
    if (err != hipSuccess) {
        gru_seq_kernel<<<dim3(512), dim3(256), 0, stream>>>(
            x, h0, w_ih, w_hh, b_ih, b_hh, out, h_final, flags);
    }

    post2_kernel<<<dim3(kB * kT / 16), dim3(128), 0, stream>>>(wpT, b_post, out);
}

// Round 11
// 5615.019 us; speedup vs baseline: 2.3927x; 2.3927x over previous
//
#include <hip/hip_runtime.h>

constexpr int kB = 64;
constexpr int kT = 1024;
constexpr int kC = 128;
constexpr int kH = 512;

constexpr int kWgPerGrp = 32;   // wgs per group (16 cols each)
constexpr int kRows     = 4;    // batches per group
constexpr int kHStride  = 652;  // hbuf row: 512 h + 128 x + 12 pad floats

#define SCOPE_AGENT __HIP_MEMORY_SCOPE_AGENT

__device__ __forceinline__ float sigmoidf_(float v) {
    return 1.0f / (1.0f + __expf(-v));
}

// Persistent GRU. 512 wgs x 256 threads (4 waves), 2 wgs/CU (10.4KB LDS each).
// 16 groups x 32 wgs. Mapping (R11 FIX): grp = ((wg&7)<<1) | ((wg>>8)&1),
// jb = (wg>>3)&31. Properties:
//  - group XCD-clustered: all wgs of a group share wg&7 -> same XCD under
//    round-robin placement (L2 locality for h staging, R5/R7-proven).
//  - co-resident pair (k, k+256) under breadth-first dispatch differs in
//    (wg>>8)&1 -> DIFFERENT, fully independent groups on each CU -> true
//    anti-phased latency hiding. [R7 bug: grp used (wg>>3)&1, which is equal
//    for k and k+256 -> same group co-resident -> CU idle during the whole
//    publish->flag->poll->stage chain. That was ~3µs/step of the 5.8µs.]
// Correctness does NOT depend on placement.
// Group g owns batches [g*4, g*4+4); wg owns output columns [jb*16,+16).
// h-exchange through hs_out: finishers publish with relaxed agent-scope
// atomic stores (MALL-visible); consumers stage hs_out[:, t-1, :] with plain
// coalesced float4 loads — fresh addresses every step, no stale-cache risk.
// Ordering: atomic store -> __syncthreads (vmcnt drain) -> flag store;
// reader: poll flags -> plain load.
// Weights in registers: whR[4][3][2] + wiR[3][2]. LDS = hbuf only.
// Thread map: tid = jp(3b)|s(5b); strided K-split h-k4 = s + 32m, x-k4 = s.
// Reduce-scatter xor{8,4,2} + butterflies xor{16,1}; finishers even s<16.
// Per-step sync: all-report flag barrier (32 flags, polled by lanes tid<32).
__global__ __launch_bounds__(256, 2)
void gru_seq_kernel(const float* __restrict__ x,
                    const float* __restrict__ h0,
                    const float* __restrict__ w_ih,
                    const float* __restrict__ w_hh,
                    const float* __restrict__ b_ih,
                    const float* __restrict__ b_hh,
                    float* __restrict__ hs_out,   // d_out, [B,T,H]; also h-exchange
                    float* __restrict__ h_final,  // d_out + B*T*H
                    unsigned* __restrict__ flags) // d_ws: 16 x 32 uints
{
    const int wg  = blockIdx.x;
    const int grp = ((wg & 7) << 1) | ((wg >> 8) & 1);   // 0..15 (R11 fix)
    const int jb  = (wg >> 3) & 31;                      // 0..31
    const int tid = threadIdx.x;
    const int jp  = tid >> 5;                    // 0..7 (j-pair)
    const int s   = tid & 31;                    // K-slice (lane bits 0-4)
    const int b0  = grp * kRows;

    __shared__ float hbuf[kRows][kHStride];      // 10,432 B ([h | x] per row)

    // ---- one-time weight loads into REGISTERS ----
    const float4* w_hh4 = (const float4*)w_hh;
    const float4* w_ih4 = (const float4*)w_ih;
    float4 whR[4][3][2];   // [m][gate][jj]
    #pragma unroll
    for (int m = 0; m < 4; ++m)
        #pragma unroll
        for (int g = 0; g < 3; ++g)
            #pragma unroll
            for (int jj = 0; jj < 2; ++jj)
                whR[m][g][jj] =
                    w_hh4[((size_t)(g * kH + jb * 16 + jp * 2 + jj)) * (kH / 4)
                          + s + 32 * m];
    float4 wiR[3][2];      // [gate][jj] at x-f4 = s
    #pragma unroll
    for (int g = 0; g < 3; ++g)
        #pragma unroll
        for (int jj = 0; jj < 2; ++jj)
            wiR[g][jj] =
                w_ih4[((size_t)(g * kH + jb * 16 + jp * 2 + jj)) * (kC / 4) + s];

    // biases for this thread's finish output (finishers: even s < 16)
    const int jg_f = jb * 16 + jp * 2 + ((s >> 1) & 1);
    const float brz = b_ih[jg_f]          + b_hh[jg_f];
    const float bzz = b_ih[kH + jg_f]     + b_hh[kH + jg_f];
    const float bxn = b_ih[2 * kH + jg_f];
    const float bhn = b_hh[2 * kH + jg_f];

    unsigned* myflag = flags + grp * kWgPerGrp + jb;
    const unsigned* pollflag = flags + grp * kWgPerGrp + (tid & 31);

    // all-report barrier: store own epoch flag, lanes tid<32 poll all 32
    auto group_barrier = [&](unsigned e) {
        __syncthreads();   // vmcnt(0) drain: prior (atomic) stores MALL-visible
        if (tid < kWgPerGrp) {
            if (tid == 0)
                __hip_atomic_store(myflag, e, __ATOMIC_RELAXED, SCOPE_AGENT);
            unsigned v;
            do {
                v = __hip_atomic_load(pollflag, __ATOMIC_RELAXED, SCOPE_AGENT);
            } while (__any((int)(v < e)));
        }
        __syncthreads();
    };

    for (int t = 0; t < kT; ++t) {
        // ---- stage h rows: PLAIN float4 loads, 2 per thread ----
        {
            #pragma unroll
            for (int qq = 0; qq < 2; ++qq) {
                const int idx = tid + qq * 256;    // 0..511
                const int row = idx >> 7;          // 0..3
                const int f4  = idx & 127;
                float4 v;
                if (t == 0)
                    v = *(const float4*)&h0[(size_t)(b0 + row) * kH + f4 * 4];
                else
                    v = *(const float4*)
                        &hs_out[((size_t)(b0 + row) * kT + (t - 1)) * kH + f4 * 4];
                *(float4*)&hbuf[row][f4 * 4] = v;
            }
        }
        if (t == 0) {   // steady-state x is prefetched at the end of prev iter
            if (tid < 128) {
                const int row = tid >> 5;          // 0..3
                const int f4i = tid & 31;
                *(float4*)&hbuf[row][512 + f4i * 4] =
                    *(const float4*)&x[((size_t)(b0 + row) * kT + 0) * kC + f4i * 4];
            }
        }
        __syncthreads();

        // ---- gate dots: acc[{r,z,n_h,n_x}][4 rows][2 j] ----
        float acc[4][4][2];
        #pragma unroll
        for (int g = 0; g < 4; ++g)
            #pragma unroll
            for (int i = 0; i < 4; ++i) {
                acc[g][i][0] = 0.f; acc[g][i][1] = 0.f;
            }

        const float* hbase = &hbuf[0][s * 4];

        #pragma unroll
        for (int m = 0; m < 4; ++m) {         // h-part: k4 = s + 32m
            const int off = m * 128;
            float4 h4[4];
            #pragma unroll
            for (int i = 0; i < 4; ++i)
                h4[i] = *(const float4*)(hbase + i * kHStride + off);
            #pragma unroll
            for (int g = 0; g < 3; ++g)
                #pragma unroll
                for (int jj = 0; jj < 2; ++jj) {
                    const float4 w4 = whR[m][g][jj];
                    #pragma unroll
                    for (int i = 0; i < 4; ++i)
                        acc[g][i][jj] += h4[i].x * w4.x + h4[i].y * w4.y
                                       + h4[i].z * w4.z + h4[i].w * w4.w;
                }
        }
        {   // x-part: x-f4 = s (weights in registers)
            float4 x4v[4];
            #pragma unroll
            for (int i = 0; i < 4; ++i)
                x4v[i] = *(const float4*)(hbase + i * kHStride + 512);
            #pragma unroll
            for (int g = 0; g < 3; ++g) {
                const int ga = (g == 2) ? 3 : g;   // x-side n goes to acc[3]
                #pragma unroll
                for (int jj = 0; jj < 2; ++jj) {
                    const float4 w4 = wiR[g][jj];
                    #pragma unroll
                    for (int i = 0; i < 4; ++i)
                        acc[ga][i][jj] += x4v[i].x * w4.x + x4v[i].y * w4.y
                                        + x4v[i].z * w4.z + x4v[i].w * w4.w;
                }
            }
        }

        // ---- reduce-scatter over s: xor{8,4,2} + butterflies xor{16,1}.
        // Owner bits: row = b3*2 + b2, jj = b1; bits {0,4} redundant.
        const bool b3 = (s >> 3) & 1;
        const bool b2 = (s >> 2) & 1;
        const bool b1 = (s >> 1) & 1;

        float A[4][2][2];
        #pragma unroll
        for (int g = 0; g < 4; ++g)
            #pragma unroll
            for (int ii = 0; ii < 2; ++ii)
                #pragma unroll
                for (int jj = 0; jj < 2; ++jj) {
                    const float keep = b3 ? acc[g][2 + ii][jj] : acc[g][ii][jj];
                    const float send = b3 ? acc[g][ii][jj] : acc[g][2 + ii][jj];
                    A[g][ii][jj] = keep + __shfl_xor(send, 8);
                }
        float Bv[4][2];
        #pragma unroll
        for (int g = 0; g < 4; ++g)
            #pragma unroll
            for (int jj = 0; jj < 2; ++jj) {
                const float keep = b2 ? A[g][1][jj] : A[g][0][jj];
                const float send = b2 ? A[g][0][jj] : A[g][1][jj];
                Bv[g][jj] = keep + __shfl_xor(send, 4);
            }
        float Dv[4];
        #pragma unroll
        for (int g = 0; g < 4; ++g) {
            const float keep = b1 ? Bv[g][1] : Bv[g][0];
            const float send = b1 ? Bv[g][0] : Bv[g][1];
            float c = keep + __shfl_xor(send, 2);
            c += __shfl_xor(c, 16);
            c += __shfl_xor(c, 1);
            Dv[g] = c;
        }

        __syncthreads();   // all compute reads of hbuf x-section done

        // ---- prefetch x for step t+1 into hbuf x-section ----
        if (t + 1 < kT && tid < 128) {
            const int row = tid >> 5;
            const int f4i = tid & 31;
            *(float4*)&hbuf[row][512 + f4i * 4] =
                *(const float4*)&x[((size_t)(b0 + row) * kT + (t + 1)) * kC + f4i * 4];
        }

        // ---- finish: even lanes s<16 own output (row = b3*2+b2, jj = b1) ----
        if (s < 16 && (s & 1) == 0) {
            const int   row  = ((s >> 3) & 1) * 2 + ((s >> 2) & 1);
            const int   bg   = b0 + row;
            const float rg   = sigmoidf_(Dv[0] + brz);
            const float zg   = sigmoidf_(Dv[1] + bzz);
            const float ng   = tanhf(Dv[3] + bxn + rg * (Dv[2] + bhn));
            const float hold = hbuf[row][jg_f];
            const float hnew = (1.f - zg) * ng + zg * hold;

            // single h-publish: atomic (MALL-visible) store into hs_out
            __hip_atomic_store(&hs_out[((size_t)bg * kT + t) * kH + jg_f], hnew,
                               __ATOMIC_RELAXED, SCOPE_AGENT);
            if (t == kT - 1) h_final[(size_t)bg * kH + jg_f] = hnew;
        }

        group_barrier((unsigned)(t + 1));
    }
}

// 32x32 tiled transpose: wpT[k][d] = w_post[d][k].  (R10-proven)
__global__ __launch_bounds__(256)
void wpt_kernel(const float* __restrict__ w_post, float* __restrict__ wpT)
{
    __shared__ float tile[32][33];
    const int bx = blockIdx.x & 15, by = blockIdx.x >> 4;
    const int tx = threadIdx.x & 31, ty = threadIdx.x >> 5;   // 32 x 8
    #pragma unroll
    for (int i = 0; i < 4; ++i)
        tile[ty + i * 8][tx] =
            w_post[(size_t)(by * 32 + ty + i * 8) * kH + bx * 32 + tx];
    __syncthreads();
    #pragma unroll
    for (int i = 0; i < 4; ++i)
        wpT[(size_t)(bx * 32 + ty + i * 8) * kH + by * 32 + tx] =
            tile[tx][ty + i * 8];
}

// In-place post projection, coalesced-w (R10-proven, ~190us incl. wpt):
// out[b,t,:] = relu(hs[b,t,:] @ w_post^T + b_post), using wpT[k][d].
__global__ __launch_bounds__(128)
void post2_kernel(const float* __restrict__ wpT,
                  const float* __restrict__ b_post,
                  float* __restrict__ out)
{
    __shared__ float hb[16][kH];
    const int tid = threadIdx.x;
    const size_t row0 = (size_t)blockIdx.x * 16;

    const float4* src = (const float4*)(out + row0 * kH);
    float4* hb4 = (float4*)hb;
    for (int i = tid; i < 16 * kH / 4; i += 128) hb4[i] = src[i];
    __syncthreads();

    float4 acc[16];
    #pragma unroll
    for (int m = 0; m < 16; ++m) acc[m] = make_float4(0.f, 0.f, 0.f, 0.f);

    const float4* wT4 = (const float4*)wpT;
    for (int k4 = 0; k4 < kH / 4; ++k4) {
        const float4 w0 = wT4[(size_t)(k4 * 4 + 0) * 128 + tid];
        const float4 w1 = wT4[(size_t)(k4 * 4 + 1) * 128 + tid];
        const float4 w2 = wT4[(size_t)(k4 * 4 + 2) * 128 + tid];
        const float4 w3 = wT4[(size_t)(k4 * 4 + 3) * 128 + tid];
        #pragma unroll
        for (int m = 0; m < 16; ++m) {
            const float4 h4 = *(const float4*)&hb[m][k4 * 4];
            acc[m].x += h4.x * w0.x + h4.y * w1.x + h4.z * w2.x + h4.w * w3.x;
            acc[m].y += h4.x * w0.y + h4.y * w1.y + h4.z * w2.y + h4.w * w3.y;
            acc[m].z += h4.x * w0.z + h4.y * w1.z + h4.z * w2.z + h4.w * w3.z;
            acc[m].w += h4.x * w0.w + h4.y * w1.w + h4.z * w2.w + h4.w * w3.w;
        }
    }

    const float4 bp = *(const float4*)&b_post[tid * 4];
    #pragma unroll
    for (int m = 0; m < 16; ++m) {
        float4 r;
        r.x = fmaxf(acc[m].x + bp.x, 0.f);
        r.y = fmaxf(acc[m].y + bp.y, 0.f);
        r.z = fmaxf(acc[m].z + bp.z, 0.f);
        r.w = fmaxf(acc[m].w + bp.w, 0.f);
        *(float4*)&out[(row0 + m) * kH + tid * 4] = r;
    }
}

extern "C" void kernel_launch(void* const* d_in, const int* in_sizes, int n_in,
                              void* d_out, int out_size, void* d_ws, size_t ws_size,
                              hipStream_t stream) {
    const float* x      = (const float*)d_in[0];
    const float* h0     = (const float*)d_in[1];
    const float* w_ih   = (const float*)d_in[2];
    const float* w_hh   = (const float*)d_in[3];
    const float* b_ih   = (const float*)d_in[4];
    const float* b_hh   = (const float*)d_in[5];
    const float* w_post = (const float*)d_in[6];
    const float* b_post = (const float*)d_in[7];

    float* out     = (float*)d_out;
    float* h_final = out + (size_t)kB * kT * kH;

    unsigned* flags = (unsigned*)d_ws;                  // 16 x 32 uints = 2 KB
    float* wpT      = (float*)((char*)d_ws + 8192);     // 512 x 512 = 1 MB

    // flags must start at 0 every launch (d_ws is not re-poisoned per replay)
    hipMemsetAsync(d_ws, 0, 8192, stream);

    // transpose w_post (independent; stream-ordered before post2)
    wpt_kernel<<<dim3(256), dim3(256), 0, stream>>>(w_post, wpT);

    void* args[] = { (void*)&x, (void*)&h0, (void*)&w_ih, (void*)&w_hh,
                     (void*)&b_ih, (void*)&b_hh, (void*)&out, (void*)&h_final,
                     (void*)&flags };
    // Cooperative launch for guaranteed co-residency; fall back to plain
    // launch if refused (512 wgs at 2/CU co-resident in practice).
    hipError_t err = hipLaunchCooperativeKernel((void*)gru_seq_kernel,
                                                dim3(512), dim3(256),
                                                args, 0, stream);
    if (err != hipSuccess) {
        gru_seq_kernel<<<dim3(512), dim3(256), 0, stream>>>(
            x, h0, w_ih, w_hh, b_ih, b_hh, out, h_final, flags);
    }

    post2_kernel<<<dim3(kB * kT / 16), dim3(128), 0, stream>>>(wpT, b_post, out);
}

// Round 12
// 4385.023 us; speedup vs baseline: 3.0639x; 1.2805x over previous
//
#include <hip/hip_runtime.h>

constexpr int kB = 64;
constexpr int kT = 1024;
constexpr int kC = 128;
constexpr int kH = 512;

constexpr int kWgPerGrp = 32;   // wgs per group (16 cols each)
constexpr int kRows     = 4;    // batches per group
constexpr int kHStride  = 652;  // hbuf row: 512 h + 128 x + 12 pad floats

#define SCOPE_AGENT __HIP_MEMORY_SCOPE_AGENT

__device__ __forceinline__ float sigmoidf_(float v) {
    return 1.0f / (1.0f + __expf(-v));
}

__device__ __forceinline__ void fma4_(float& a, const float4 h, const float4 w) {
    a = fmaf(h.x, w.x, a);
    a = fmaf(h.y, w.y, a);
    a = fmaf(h.z, w.z, a);
    a = fmaf(h.w, w.w, a);
}

// Persistent GRU. 512 wgs x 256 threads (4 waves), 2 wgs/CU (10.4KB LDS each).
// 16 groups x 32 wgs. Mapping (R11-proven): grp = ((wg&7)<<1) | ((wg>>8)&1),
// jb = (wg>>3)&31 — group XCD-clustered (L2 locality) AND co-resident pair
// (k, k+256) in different independent groups (anti-phased latency hiding).
// Group g owns batches [g*4, g*4+4); wg owns output columns [jb*16,+16).
// h-exchange through hs_out: finishers publish with relaxed agent-scope
// atomic stores (MALL-visible); consumers stage hs_out[:, t-1, :] with plain
// coalesced float4 loads — fresh addresses every step, no stale-cache risk.
// R12 step pipeline (latency-hiding reorder; orderings audited):
//   1. issue h staging loads (regs)          [MALL ~700cy in flight]
//   2. x-part FMAs (reads x-section, staged pre-barrier)   [covers 1]
//   3. LDS-write staged h; __syncthreads
//   4. issue x(t+1) global load (regs)       [HBM ~900cy in flight]
//   5. h-part FMAs; 6. reduce-scatter        [covers 4]
//   7. write x(t+1) regs -> x-section (safe: all waves passed sync-3)
//   8. finish + publish; 9. flag barrier
// All FMA loops use explicit fmaf chains (guaranteed v_fmac contraction).
// Thread map: tid = jp(3b)|s(5b); strided K-split h-k4 = s + 32m, x-k4 = s.
// Reduce-scatter xor{8,4,2} + butterflies xor{16,1}; finishers even s<16.
__global__ __launch_bounds__(256, 2)
void gru_seq_kernel(const float* __restrict__ x,
                    const float* __restrict__ h0,
                    const float* __restrict__ w_ih,
                    const float* __restrict__ w_hh,
                    const float* __restrict__ b_ih,
                    const float* __restrict__ b_hh,
                    float* __restrict__ hs_out,   // d_out, [B,T,H]; also h-exchange
                    float* __restrict__ h_final,  // d_out + B*T*H
                    unsigned* __restrict__ flags) // d_ws: 16 x 32 uints
{
    const int wg  = blockIdx.x;
    const int grp = ((wg & 7) << 1) | ((wg >> 8) & 1);   // 0..15
    const int jb  = (wg >> 3) & 31;                      // 0..31
    const int tid = threadIdx.x;
    const int jp  = tid >> 5;                    // 0..7 (j-pair)
    const int s   = tid & 31;                    // K-slice (lane bits 0-4)
    const int b0  = grp * kRows;

    __shared__ float hbuf[kRows][kHStride];      // 10,432 B ([h | x] per row)

    // ---- one-time weight loads into REGISTERS ----
    const float4* w_hh4 = (const float4*)w_hh;
    const float4* w_ih4 = (const float4*)w_ih;
    float4 whR[4][3][2];   // [m][gate][jj]
    #pragma unroll
    for (int m = 0; m < 4; ++m)
        #pragma unroll
        for (int g = 0; g < 3; ++g)
            #pragma unroll
            for (int jj = 0; jj < 2; ++jj)
                whR[m][g][jj] =
                    w_hh4[((size_t)(g * kH + jb * 16 + jp * 2 + jj)) * (kH / 4)
                          + s + 32 * m];
    float4 wiR[3][2];      // [gate][jj] at x-f4 = s
    #pragma unroll
    for (int g = 0; g < 3; ++g)
        #pragma unroll
        for (int jj = 0; jj < 2; ++jj)
            wiR[g][jj] =
                w_ih4[((size_t)(g * kH + jb * 16 + jp * 2 + jj)) * (kC / 4) + s];

    // biases for this thread's finish output (finishers: even s < 16)
    const int jg_f = jb * 16 + jp * 2 + ((s >> 1) & 1);
    const float brz = b_ih[jg_f]          + b_hh[jg_f];
    const float bzz = b_ih[kH + jg_f]     + b_hh[kH + jg_f];
    const float bxn = b_ih[2 * kH + jg_f];
    const float bhn = b_hh[2 * kH + jg_f];

    unsigned* myflag = flags + grp * kWgPerGrp + jb;
    const unsigned* pollflag = flags + grp * kWgPerGrp + (tid & 31);

    // all-report barrier: store own epoch flag, lanes tid<32 poll all 32
    auto group_barrier = [&](unsigned e) {
        __syncthreads();   // vmcnt(0) drain: prior (atomic) stores MALL-visible
        if (tid < kWgPerGrp) {
            if (tid == 0)
                __hip_atomic_store(myflag, e, __ATOMIC_RELAXED, SCOPE_AGENT);
            unsigned v;
            do {
                v = __hip_atomic_load(pollflag, __ATOMIC_RELAXED, SCOPE_AGENT);
            } while (__any((int)(v < e)));
        }
        __syncthreads();
    };

    // ---- prologue: stage h0 and x(0) into LDS ----
    #pragma unroll
    for (int qq = 0; qq < 2; ++qq) {
        const int idx = tid + qq * 256;
        const int row = idx >> 7;
        const int f4  = idx & 127;
        *(float4*)&hbuf[row][f4 * 4] =
            *(const float4*)&h0[(size_t)(b0 + row) * kH + f4 * 4];
    }
    if (tid < 128) {
        const int row = tid >> 5;
        const int f4i = tid & 31;
        *(float4*)&hbuf[row][512 + f4i * 4] =
            *(const float4*)&x[((size_t)(b0 + row) * kT + 0) * kC + f4i * 4];
    }
    __syncthreads();

    const int st_row0 = tid >> 7;            // staging rows/cols for this thread
    const int st_f40  = tid & 127;
    const int st_row1 = (tid + 256) >> 7;
    const int st_f41  = (tid + 256) & 127;

    for (int t = 0; t < kT; ++t) {
        // ---- (1) issue h staging loads (plain coalesced, fresh addresses) ----
        float4 hv0, hv1;
        if (t > 0) {
            hv0 = *(const float4*)
                &hs_out[((size_t)(b0 + st_row0) * kT + (t - 1)) * kH + st_f40 * 4];
            hv1 = *(const float4*)
                &hs_out[((size_t)(b0 + st_row1) * kT + (t - 1)) * kH + st_f41 * 4];
        }

        // ---- (2) x-part FMAs (h-independent; covers the loads' latency) ----
        float acc[4][4][2];
        #pragma unroll
        for (int g = 0; g < 4; ++g)
            #pragma unroll
            for (int i = 0; i < 4; ++i) {
                acc[g][i][0] = 0.f; acc[g][i][1] = 0.f;
            }
        {
            float4 x4v[4];
            #pragma unroll
            for (int i = 0; i < 4; ++i)
                x4v[i] = *(const float4*)(&hbuf[i][512 + s * 4]);
            #pragma unroll
            for (int g = 0; g < 3; ++g) {
                const int ga = (g == 2) ? 3 : g;   // x-side n -> acc[3]
                #pragma unroll
                for (int jj = 0; jj < 2; ++jj) {
                    const float4 w4 = wiR[g][jj];
                    #pragma unroll
                    for (int i = 0; i < 4; ++i)
                        fma4_(acc[ga][i][jj], x4v[i], w4);
                }
            }
        }

        // ---- (3) LDS-write staged h; sync ----
        if (t > 0) {
            *(float4*)&hbuf[st_row0][st_f40 * 4] = hv0;
            *(float4*)&hbuf[st_row1][st_f41 * 4] = hv1;
        }
        __syncthreads();   // staging visible; prior x-section reads done

        // ---- (4) issue x(t+1) load (latency hidden under h-part+reduce) ----
        float4 xnext;
        const bool do_x = (t + 1 < kT) && (tid < 128);
        if (do_x) {
            const int row = tid >> 5;
            const int f4i = tid & 31;
            xnext = *(const float4*)
                &x[((size_t)(b0 + row) * kT + (t + 1)) * kC + f4i * 4];
        }

        // ---- (5) h-part FMAs ----
        const float* hbase = &hbuf[0][s * 4];
        #pragma unroll
        for (int m = 0; m < 4; ++m) {         // h-k4 = s + 32m
            const int off = m * 128;
            float4 h4[4];
            #pragma unroll
            for (int i = 0; i < 4; ++i)
                h4[i] = *(const float4*)(hbase + i * kHStride + off);
            #pragma unroll
            for (int g = 0; g < 3; ++g)
                #pragma unroll
                for (int jj = 0; jj < 2; ++jj) {
                    const float4 w4 = whR[m][g][jj];
                    #pragma unroll
                    for (int i = 0; i < 4; ++i)
                        fma4_(acc[g][i][jj], h4[i], w4);
                }
        }

        // ---- (6) reduce-scatter xor{8,4,2} + butterflies xor{16,1} ----
        const bool b3 = (s >> 3) & 1;
        const bool b2 = (s >> 2) & 1;
        const bool b1 = (s >> 1) & 1;

        float A[4][2][2];
        #pragma unroll
        for (int g = 0; g < 4; ++g)
            #pragma unroll
            for (int ii = 0; ii < 2; ++ii)
                #pragma unroll
                for (int jj = 0; jj < 2; ++jj) {
                    const float keep = b3 ? acc[g][2 + ii][jj] : acc[g][ii][jj];
                    const float send = b3 ? acc[g][ii][jj] : acc[g][2 + ii][jj];
                    A[g][ii][jj] = keep + __shfl_xor(send, 8);
                }
        float Bv[4][2];
        #pragma unroll
        for (int g = 0; g < 4; ++g)
            #pragma unroll
            for (int jj = 0; jj < 2; ++jj) {
                const float keep = b2 ? A[g][1][jj] : A[g][0][jj];
                const float send = b2 ? A[g][0][jj] : A[g][1][jj];
                Bv[g][jj] = keep + __shfl_xor(send, 4);
            }
        float Dv[4];
        #pragma unroll
        for (int g = 0; g < 4; ++g) {
            const float keep = b1 ? Bv[g][1] : Bv[g][0];
            const float send = b1 ? Bv[g][0] : Bv[g][1];
            float c = keep + __shfl_xor(send, 2);
            c += __shfl_xor(c, 16);
            c += __shfl_xor(c, 1);
            Dv[g] = c;
        }

        // ---- (7) write x(t+1) into x-section (all waves passed sync-3) ----
        if (do_x) {
            const int row = tid >> 5;
            const int f4i = tid & 31;
            *(float4*)&hbuf[row][512 + f4i * 4] = xnext;
        }

        // ---- (8) finish + publish (even lanes s<16; row = b3*2+b2, jj = b1) ----
        if (s < 16 && (s & 1) == 0) {
            const int   row  = ((s >> 3) & 1) * 2 + ((s >> 2) & 1);
            const int   bg   = b0 + row;
            const float rg   = sigmoidf_(Dv[0] + brz);
            const float zg   = sigmoidf_(Dv[1] + bzz);
            const float ng   = tanhf(Dv[3] + bxn + rg * (Dv[2] + bhn));
            const float hold = hbuf[row][jg_f];
            const float hnew = (1.f - zg) * ng + zg * hold;

            __hip_atomic_store(&hs_out[((size_t)bg * kT + t) * kH + jg_f], hnew,
                               __ATOMIC_RELAXED, SCOPE_AGENT);
            if (t == kT - 1) h_final[(size_t)bg * kH + jg_f] = hnew;
        }

        // ---- (9) barrier ----
        group_barrier((unsigned)(t + 1));
    }
}

// 32x32 tiled transpose: wpT[k][d] = w_post[d][k].  (R10-proven)
__global__ __launch_bounds__(256)
void wpt_kernel(const float* __restrict__ w_post, float* __restrict__ wpT)
{
    __shared__ float tile[32][33];
    const int bx = blockIdx.x & 15, by = blockIdx.x >> 4;
    const int tx = threadIdx.x & 31, ty = threadIdx.x >> 5;   // 32 x 8
    #pragma unroll
    for (int i = 0; i < 4; ++i)
        tile[ty + i * 8][tx] =
            w_post[(size_t)(by * 32 + ty + i * 8) * kH + bx * 32 + tx];
    __syncthreads();
    #pragma unroll
    for (int i = 0; i < 4; ++i)
        wpT[(size_t)(bx * 32 + ty + i * 8) * kH + by * 32 + tx] =
            tile[tx][ty + i * 8];
}

// In-place post projection, coalesced-w (R10-proven, ~FLOP-floor):
// out[b,t,:] = relu(hs[b,t,:] @ w_post^T + b_post), using wpT[k][d].
__global__ __launch_bounds__(128)
void post2_kernel(const float* __restrict__ wpT,
                  const float* __restrict__ b_post,
                  float* __restrict__ out)
{
    __shared__ float hb[16][kH];
    const int tid = threadIdx.x;
    const size_t row0 = (size_t)blockIdx.x * 16;

    const float4* src = (const float4*)(out + row0 * kH);
    float4* hb4 = (float4*)hb;
    for (int i = tid; i < 16 * kH / 4; i += 128) hb4[i] = src[i];
    __syncthreads();

    float4 acc[16];
    #pragma unroll
    for (int m = 0; m < 16; ++m) acc[m] = make_float4(0.f, 0.f, 0.f, 0.f);

    const float4* wT4 = (const float4*)wpT;
    for (int k4 = 0; k4 < kH / 4; ++k4) {
        const float4 w0 = wT4[(size_t)(k4 * 4 + 0) * 128 + tid];
        const float4 w1 = wT4[(size_t)(k4 * 4 + 1) * 128 + tid];
        const float4 w2 = wT4[(size_t)(k4 * 4 + 2) * 128 + tid];
        const float4 w3 = wT4[(size_t)(k4 * 4 + 3) * 128 + tid];
        #pragma unroll
        for (int m = 0; m < 16; ++m) {
            const float4 h4 = *(const float4*)&hb[m][k4 * 4];
            acc[m].x = fmaf(h4.x, w0.x, fmaf(h4.y, w1.x, fmaf(h4.z, w2.x, fmaf(h4.w, w3.x, acc[m].x))));
            acc[m].y = fmaf(h4.x, w0.y, fmaf(h4.y, w1.y, fmaf(h4.z, w2.y, fmaf(h4.w, w3.y, acc[m].y))));
            acc[m].z = fmaf(h4.x, w0.z, fmaf(h4.y, w1.z, fmaf(h4.z, w2.z, fmaf(h4.w, w3.z, acc[m].z))));
            acc[m].w = fmaf(h4.x, w0.w, fmaf(h4.y, w1.w, fmaf(h4.z, w2.w, fmaf(h4.w, w3.w, acc[m].w))));
        }
    }

    const float4 bp = *(const float4*)&b_post[tid * 4];
    #pragma unroll
    for (int m = 0; m < 16; ++m) {
        float4 r;
        r.x = fmaxf(acc[m].x + bp.x, 0.f);
        r.y = fmaxf(acc[m].y + bp.y, 0.f);
        r.z = fmaxf(acc[m].z + bp.z, 0.f);
        r.w = fmaxf(acc[m].w + bp.w, 0.f);
        *(float4*)&out[(row0 + m) * kH + tid * 4] = r;
    }
}

extern "C" void kernel_launch(void* const* d_in, const int* in_sizes, int n_in,
                              void* d_out, int out_size, void* d_ws, size_t ws_size,
                              hipStream_t stream) {
    const float* x      = (const float*)d_in[0];
    const float* h0     = (const float*)d_in[1];
    const float* w_ih   = (const float*)d_in[2];
    const float* w_hh   = (const float*)d_in[3];
    const float* b_ih   = (const float*)d_in[4];
    const float* b_hh   = (const float*)d_in[5];
    const float* w_post = (const float*)d_in[6];
    const float* b_post = (const float*)d_in[7];

    float* out     = (float*)d_out;
    float* h_final = out + (size_t)kB * kT * kH;

    unsigned* flags = (unsigned*)d_ws;                  // 16 x 32 uints = 2 KB
    float* wpT      = (float*)((char*)d_ws + 8192);     // 512 x 512 = 1 MB

    // flags must start at 0 every launch (d_ws is not re-poisoned per replay)
    hipMemsetAsync(d_ws, 0, 8192, stream);

    // transpose w_post (independent; stream-ordered before post2)
    wpt_kernel<<<dim3(256), dim3(256), 0, stream>>>(w_post, wpT);

    void* args[] = { (void*)&x, (void*)&h0, (void*)&w_ih, (void*)&w_hh,
                     (void*)&b_ih, (void*)&b_hh, (void*)&out, (void*)&h_final,
                     (void*)&flags };
    // Cooperative launch for guaranteed co-residency; fall back to plain
    // launch if refused (512 wgs at 2/CU co-resident in practice).
    hipError_t err = hipLaunchCooperativeKernel((void*)gru_seq_kernel,
                                                dim3(512), dim3(256),
                                                args, 0, stream);
    if (err != hipSuccess) {
        gru_seq_kernel<<<dim3(512), dim3(256), 0, stream>>>(
            x, h0, w_ih, w_hh, b_ih, b_hh, out, h_final, flags);
    }

    post2_kernel<<<dim3(kB * kT / 16), dim3(128), 0, stream>>>(wpT, b_post, out);
}